// Round 9
// baseline (176.111 us; speedup 1.0000x reference)
//
#include <hip/hip_runtime.h>
#include <hip/hip_fp16.h>
#include <math.h>
#include <stdint.h>

// VocosISTFTHead on MI355X.
//  K0 convert_AB: fused. Blocks <2048: hs -> Af fp16 plane + Nyquist spec col
//                 (full f32 dot) -> coeffs slot[1]. Blocks >=2048: W -> tiled
//                 fp16 plane Whi [yb4][kt16][r256][k32].
//  K1 gemm_mfma : spec = hs @ W.T + b via single fp16 MFMA (Af x Whi).
//                 256 rows x 128 col-pairs per block, 1024 threads / 16 waves
//                 (4M x 4N, wave = 64 rows x 32 pairs, acc = 64 f32/lane ->
//                 total regs <= 128 -> 4 waves/SIMD; round-6 lesson: raise
//                 occupancy by splitting the SAME block, not shrinking it).
//                 A LDS triple-buffer + cross-phase frag prefetch; counted
//                 vmcnt(1)/vmcnt(5) (T4, never 0 until last); B L2->regs
//                 prefetched 1 K-step ahead.
//  K2 fft_win   : 1024-pt real iFFT per frame (512-pt complex Stockham radix-8),
//                 fp16 coeffs in (aligned 1024-half rows), fp16 frames out.
//  K3 gather_out: deterministic overlap-add gather + window^2 normalization.
// coeffs row layout (1024 halves, 2048B aligned): [0]=DC real, [1]=Nyquist real,
//   complex k (k=1..511) at halves [2k, 2k+2).
// ws (134.2 MB):
//   [0 : 33.55M) Af | [33.55M : 34.60M) Whi | later frames fp16 [0 : 67.11M)
//   [67.11M : 134.22M) coeffs fp16 (32768 x 1024 halves)

#define FRAMES  32768
#define TWO_PI  6.283185307179586f

typedef unsigned short ushort_t;
typedef __attribute__((ext_vector_type(8))) _Float16 f16x8;
typedef __attribute__((ext_vector_type(4))) float f32x4;

#define GLDS(gp, lp) __builtin_amdgcn_global_load_lds( \
    (const __attribute__((address_space(1))) void*)(gp), \
    (__attribute__((address_space(3))) void*)(lp), 16, 0, 0)

__device__ __forceinline__ float2 f2(float x, float y){ return make_float2(x,y); }
__device__ __forceinline__ float2 cadd(float2 a, float2 b){ return f2(a.x+b.x, a.y+b.y); }
__device__ __forceinline__ float2 csub(float2 a, float2 b){ return f2(a.x-b.x, a.y-b.y); }
__device__ __forceinline__ float2 cmul(float2 a, float2 b){ return f2(a.x*b.x - a.y*b.y, a.x*b.y + a.y*b.x); }

__device__ __forceinline__ uint32_t pack2h(float a, float b) {
  const ushort_t ha = __half_as_ushort(__float2half_rn(a));
  const ushort_t hb = __half_as_ushort(__float2half_rn(b));
  return (uint32_t)ha | ((uint32_t)hb << 16);
}

// ---------------------------------------------------------------------------
// K0: fused A/B conversion (unchanged, verified).
// ---------------------------------------------------------------------------
__global__ __launch_bounds__(256) void convert_AB(
    const float* __restrict__ hs, const float* __restrict__ Wm,
    const float* __restrict__ bias, ushort_t* __restrict__ Af,
    ushort_t* __restrict__ Whi, __half* __restrict__ coeffs)
{
  const int bid = blockIdx.x;
  const int t = threadIdx.x;
  if (bid < 2048) {
    const int r = t >> 4, c = t & 15;
    const int m = bid * 16 + r;
    const float* src = hs + (size_t)m * 512 + c * 32;
    const float* wm  = Wm + (size_t)512  * 512 + c * 32;
    const float* wp  = Wm + (size_t)1025 * 512 + c * 32;

    float v[32];
    #pragma unroll
    for (int i = 0; i < 8; ++i) *(float4*)&v[i*4] = *(const float4*)(src + i*4);

    float dm = 0.f, dp = 0.f;
    #pragma unroll
    for (int i = 0; i < 8; ++i) {
      const float4 a  = *(const float4*)&v[i*4];
      const float4 m4 = *(const float4*)(wm + i*4);
      const float4 p4 = *(const float4*)(wp + i*4);
      dm = fmaf(a.x,m4.x, fmaf(a.y,m4.y, fmaf(a.z,m4.z, fmaf(a.w,m4.w, dm))));
      dp = fmaf(a.x,p4.x, fmaf(a.y,p4.y, fmaf(a.z,p4.z, fmaf(a.w,p4.w, dp))));
    }

    uint32_t hu[16];
    #pragma unroll
    for (int i = 0; i < 16; ++i) hu[i] = pack2h(v[2*i], v[2*i+1]);
    ushort_t* dh = Af + (size_t)m * 512 + c * 32;
    #pragma unroll
    for (int q = 0; q < 4; ++q)
      *(uint4*)(dh + q*8) = make_uint4(hu[4*q], hu[4*q+1], hu[4*q+2], hu[4*q+3]);

    #pragma unroll
    for (int off = 8; off; off >>= 1) {
      dm += __shfl_xor(dm, off, 16);
      dp += __shfl_xor(dp, off, 16);
    }
    if (c == 0) {
      const float sm = dm + bias[512], sp = dp + bias[1025];
      const float mag = fminf(__expf(sm), 100.0f);
      coeffs[(size_t)m * 1024 + 1] = __float2half_rn(mag * __cosf(sp));
    }
  } else {
    const int gid = (bid - 2048) * 256 + t;
    const int sd = gid & 3;
    const int r  = (gid >> 2) & 255;
    const int kt = (gid >> 10) & 15;
    const int yb = gid >> 14;                        // 0..3
    const int srow = (r < 128) ? (yb*128 + r) : (513 + yb*128 + (r - 128));
    const float* src = Wm + (size_t)srow * 512 + kt*32 + sd*8;
    const float4 a = *(const float4*)src;
    const float4 b = *(const float4*)(src + 4);
    const uint4 o = make_uint4(pack2h(a.x,a.y), pack2h(a.z,a.w),
                               pack2h(b.x,b.y), pack2h(b.z,b.w));
    *(uint4*)(Whi + (size_t)gid * 8) = o;
  }
}

// ---------------------------------------------------------------------------
// K1: MFMA GEMM, 256 rows x 128 col-pairs, 1024 threads (16 waves, 4Mx4N).
// ---------------------------------------------------------------------------
__global__ __launch_bounds__(1024, 4) void gemm_mfma(
    const ushort_t* __restrict__ Af, const ushort_t* __restrict__ Whi,
    const float* __restrict__ bias, __half* __restrict__ coeffs)
{
  __shared__ ushort_t Ab[24576];       // 3 bufs x (256r x 32k) fp16 = 48KB

  const int tid = threadIdx.x;
  const int w = tid >> 6, l = tid & 63;
  const int wr = w >> 2, wc = w & 3;         // wave grid 4M x 4N
  const int lc = l & 15, kg = l >> 4;        // frag row/col, k-octet

  const int bid = blockIdx.x;                // 512 = 8 XCD * 64
  const int swz = (bid & 7) * 64 + (bid >> 3);
  const int mb = swz >> 2, yb = swz & 3;     // 4 consecutive yb per mb per XCD

  // A staging: 1 granule/thread; LDS linear, source inverse-swizzled
  // (sl = sd ^ ((r>>1)&3) => frag ds_read_b128 2-way max = free).
  uint32_t pa_off, lofs;
  {
    const int r = tid >> 2, sd = tid & 3;
    lofs = r*32 + sd*8;                      // ushort units within a 16KB buf
    const int sl = sd ^ ((r >> 1) & 3);
    pa_off = (uint32_t)(mb*256 + r)*512 + sl*8;
  }
  // B fragment sources (regs, direct from L2-resident tiled plane)
  uint32_t pb_off[4];
  #pragma unroll
  for (int cf = 0; cf < 4; ++cf) {
    const int rB = ((cf < 2) ? 0 : 128) + wc*32 + (cf & 1)*16 + lc;
    pb_off[cf] = (uint32_t)yb*131072u + rB*32 + kg*8;
  }

  f32x4 acc[4][4];                   // [rf][cf]: cf 0,1 mag; 2,3 phase
  #pragma unroll
  for (int rf = 0; rf < 4; ++rf)
    #pragma unroll
    for (int cf = 0; cf < 4; ++cf)
      #pragma unroll
      for (int q = 0; q < 4; ++q) acc[rf][cf][q] = 0.f;

  const int asl = (kg ^ ((lc >> 1) & 3)) * 8;    // frag k-slot (rf-independent)

  f16x8 p[2], q[2];    // p: frags rf0-1 (phase0); q: frags rf2-3 (phase1)

#define WAITV1 asm volatile("s_waitcnt vmcnt(1) lgkmcnt(0)" ::: "memory")
#define WAITV0 asm volatile("s_waitcnt vmcnt(0) lgkmcnt(0)" ::: "memory")
#define WAITP5 asm volatile("s_waitcnt vmcnt(5)" ::: "memory")
#define WAITP4 asm volatile("s_waitcnt vmcnt(4)" ::: "memory")
#define SB     __builtin_amdgcn_s_barrier()
#define SCH0   __builtin_amdgcn_sched_barrier(0)

#define DSREAD(DST, BASE, RF0) do {                                      \
    _Pragma("unroll")                                                    \
    for (int r4 = 0; r4 < 2; ++r4) {                                     \
      const int rr = wr*64 + ((RF0) + r4)*16 + lc;                       \
      DST[r4] = *(const f16x8*)(&Ab[(BASE) + rr*32 + asl]);              \
    }                                                                    \
  } while (0)

#define MFMA8(FA, RF0, RB) do {                                          \
    __builtin_amdgcn_s_setprio(1);                                       \
    _Pragma("unroll")                                                    \
    for (int r4 = 0; r4 < 2; ++r4)                                       \
      _Pragma("unroll")                                                  \
      for (int cf = 0; cf < 4; ++cf)                                     \
        acc[(RF0)+r4][cf] = __builtin_amdgcn_mfma_f32_16x16x32_f16(      \
            FA[r4], RB[cf], acc[(RF0)+r4][cf], 0, 0, 0);                 \
    __builtin_amdgcn_s_setprio(0);                                       \
  } while (0)

  // Steady state at step top (oldest->newest outstanding):
  // [B(KT)x4, A(KT+1)]. vmcnt(1) retires B(KT) (needed by this step's MFMAs),
  // keeps the A(KT+1) GLDS in flight across the barrier (T4). Phase 1's
  // cross-step frag prefetch reads A(KT+1) from LDS, so vmcnt(5) (KT<14;
  // outstanding then = [A(KT+1), B(KT+1)x4, A(KT+2)]) / vmcnt(4) (KT==14)
  // retires exactly A(KT+1) first.
#define ITER(KT, RBC, RBN, LAST) do {                                    \
    if (LAST) { WAITV0; } else { WAITV1; }                               \
    SB;                                                                  \
    /* phase 0: MFMA(p) ; prefetch q (this step, rf2-3) from aR */       \
    DSREAD(q, aR, 2);                                                    \
    if ((KT) < 15) {                                                     \
      _Pragma("unroll")                                                  \
      for (int j = 0; j < 4; ++j)                                        \
        RBN[j] = *(const f16x8*)(Whi + pb_off[j] + ((KT)+1)*8192);       \
    }                                                                    \
    if ((KT) < 14) GLDS(Af + pa_off + ((KT)+2)*32, &Ab[aW + lofs]);      \
    SCH0;                                                                \
    MFMA8(p, 0, RBC);                                                    \
    SB;                                                                  \
    /* phase 1: MFMA(q) ; prefetch p (next step, rf0-1) from aN */       \
    if ((KT) < 15) {                                                     \
      if ((KT) < 14) { WAITP5; } else { WAITP4; }                        \
      SCH0;                                                              \
      DSREAD(p, aN, 0);                                                  \
    }                                                                    \
    SCH0;                                                                \
    MFMA8(q, 2, RBC);                                                    \
    { const unsigned t_ = aR; aR = aN; aN = aW; aW = t_; }               \
  } while (0)

  f16x8 rb0[4], rb1[4];
  // prologue: A(0)->buf0, B(0)->rb0, A(1)->buf1 (B before A(1): ordering)
  GLDS(Af + pa_off, &Ab[lofs]);
  SCH0;
  #pragma unroll
  for (int j = 0; j < 4; ++j) rb0[j] = *(const f16x8*)(Whi + pb_off[j]);
  SCH0;
  GLDS(Af + pa_off + 32, &Ab[8192 + lofs]);
  SCH0;
  asm volatile("s_waitcnt vmcnt(5)" ::: "memory");   // A(0) retired
  SB;
  unsigned aR = 0, aN = 8192, aW = 16384;
  DSREAD(p, aR, 0);

  for (int k2 = 0; k2 < 8; ++k2) {
    ITER(2*k2,     rb0, rb1, false);
    ITER(2*k2 + 1, rb1, rb0, k2 == 7);
  }
#undef ITER
#undef DSREAD
#undef MFMA8

  // Epilogue. C/D 16x16: col = lane&15, row = (lane>>4)*4 + qi.
  // coeffs row: [0]=DC real, [1]=Nyq real, complex k at [2k] (k=1..511).
  #pragma unroll
  for (int j = 0; j < 2; ++j) {
    const int pcol = yb*128 + wc*32 + j*16 + lc;       // 0..511
    const float bm = bias[pcol], bp = bias[513 + pcol];
    #pragma unroll
    for (int rf = 0; rf < 4; ++rf) {
      const int rbase = mb*256 + wr*64 + rf*16 + kg*4;
      #pragma unroll
      for (int qi = 0; qi < 4; ++qi) {
        const float sm = acc[rf][j][qi]   + bm;
        const float sp = acc[rf][2+j][qi] + bp;
        const float mag = fminf(__expf(sm), 100.0f);
        const float aa = mag * __cosf(sp);
        const float bb = mag * __sinf(sp);
        __half* row = coeffs + (size_t)(rbase + qi) * 1024;
        if (pcol == 0) row[0] = __float2half_rn(aa);   // DC real (imag dropped)
        else *(__half2*)(row + 2*pcol) = __float22half2_rn(make_float2(aa, bb));
      }
    }
  }
}

// ---------------------------------------------------------------------------
// K2: per-frame irfft(1024) + window. fp16 coeffs in, fp16 frames out.
// ---------------------------------------------------------------------------
#define PIDX(s) ((s) + ((s) >> 3))

template<int NS>
__device__ __forceinline__ void stage_fft(const float2* in, float2* out, int l)
{
  float2 v[8];
  #pragma unroll
  for (int r = 0; r < 8; ++r) v[r] = in[PIDX(l + 64*r)];
  if (NS > 1) {
    const float ang = TWO_PI * (float)(l & (NS-1)) / (float)(NS * 8);
    float sn, cs; __sincosf(ang, &sn, &cs);
    const float2 wb = f2(cs, sn);
    float2 cur = wb;
    #pragma unroll
    for (int r = 1; r < 8; ++r) { v[r] = cmul(v[r], cur); cur = cmul(cur, wb); }
  }
  const float2 e0=v[0], e1=v[2], e2=v[4], e3=v[6];
  const float2 o0=v[1], o1=v[3], o2=v[5], o3=v[7];
  float2 a = cadd(e0,e2), b = csub(e0,e2), c = cadd(e1,e3), d = csub(e1,e3);
  const float2 E0 = cadd(a,c), E2 = csub(a,c);
  const float2 E1 = f2(b.x - d.y, b.y + d.x), E3 = f2(b.x + d.y, b.y - d.x);
  a = cadd(o0,o2); b = csub(o0,o2); c = cadd(o1,o3); d = csub(o1,o3);
  const float2 O0 = cadd(a,c), O2 = csub(a,c);
  const float2 O1 = f2(b.x - d.y, b.y + d.x), O3 = f2(b.x + d.y, b.y - d.x);
  const float r2 = 0.70710678118654752f;
  const float2 t0 = O0;
  const float2 t1 = f2(r2*(O1.x - O1.y),  r2*(O1.x + O1.y));
  const float2 t2 = f2(-O2.y, O2.x);
  const float2 t3 = f2(-r2*(O3.x + O3.y), r2*(O3.x - O3.y));
  float2 X[8];
  X[0]=cadd(E0,t0); X[4]=csub(E0,t0);
  X[1]=cadd(E1,t1); X[5]=csub(E1,t1);
  X[2]=cadd(E2,t2); X[6]=csub(E2,t2);
  X[3]=cadd(E3,t3); X[7]=csub(E3,t3);
  const int idxD = (l / NS) * (NS * 8) + (l & (NS-1));
  #pragma unroll
  for (int q = 0; q < 8; ++q) out[PIDX(idxD + q*NS)] = X[q];
}

__global__ __launch_bounds__(256) void fft_win(
    const __half* coeffs, __half* frames, const float* __restrict__ window)
{
  __shared__ float2 bA[4][576];
  __shared__ float2 bB[4][576];
  const int tid = threadIdx.x;
  const int w = tid >> 6, l = tid & 63;
  const size_t f = (size_t)blockIdx.x * 4 + w;
  const __half2* crow = (const __half2*)(coeffs + f * 1024);

  const float sc = 1.0f / 1024.0f;
  #pragma unroll
  for (int j = 0; j < 4; ++j) {
    const int k = 1 + l + 64*j;
    const float2 Ck = __half22float2(crow[k]);
    const float2 Cq = __half22float2(crow[512-k]);
    float sn, cs; __sincosf(TWO_PI * (1.0f/1024.0f) * (float)k, &sn, &cs);
    const float Ex = sc*(Ck.x + Cq.x), Ey = sc*(Ck.y - Cq.y);
    const float Dx = Ck.x - Cq.x,      Dy = Ck.y + Cq.y;
    const float Ox = sc*(cs*Dx - sn*Dy), Oy = sc*(cs*Dy + sn*Dx);
    bA[w][PIDX(k)]     = f2(Ex - Oy, Ey + Ox);
    bA[w][PIDX(512-k)] = f2(Ex + Oy, Ox - Ey);
  }
  if (l == 0) {
    const float2 dn = __half22float2(crow[0]);   // (DC real, Nyq real)
    bA[w][PIDX(0)] = f2(sc*(dn.x + dn.y), sc*(dn.x - dn.y));
  }
  __syncthreads();
  stage_fft<1 >(bA[w], bB[w], l);
  __syncthreads();
  stage_fft<8 >(bB[w], bA[w], l);
  __syncthreads();
  stage_fft<64>(bA[w], bB[w], l);
  __syncthreads();

  __half2* frow = (__half2*)(frames + f * 1024);
  #pragma unroll
  for (int j = 0; j < 8; ++j) {
    const int m = l + 64*j;
    const float2 z  = bB[w][PIDX(m)];
    const float2 wv = *(const float2*)(window + 2*m);
    frow[m] = __float22half2_rn(make_float2(z.x * wv.x, z.y * wv.y));
  }
}

// ---------------------------------------------------------------------------
// K3: overlap-add gather + normalization. fp16 frames in, f32 out.
// ---------------------------------------------------------------------------
__global__ __launch_bounds__(256) void gather_out(
    const __half* __restrict__ frames, const float* __restrict__ window,
    float* __restrict__ out)
{
  const int idx = blockIdx.x * 256 + threadIdx.x;
  const int b  = idx >> 19;
  const int jj = idx & 524287;
  const int s  = jj + 384;
  int tlo = (s - 768) >> 8; if (tlo < 0) tlo = 0;
  int thi = s >> 8;         if (thi > 2047) thi = 2047;
  float acc = 0.f, nrm = 0.f;
  for (int t = tlo; t <= thi; ++t) {
    const int n = s - (t << 8);
    const float wv = window[n];
    nrm = fmaf(wv, wv, nrm);
    acc += __half2float(frames[(size_t)(b * 2048 + t) * 1024 + n]);
  }
  out[idx] = acc / nrm;
}

// ---------------------------------------------------------------------------
extern "C" void kernel_launch(void* const* d_in, const int* in_sizes, int n_in,
                              void* d_out, int out_size, void* d_ws, size_t ws_size,
                              hipStream_t stream)
{
  const float* hs     = (const float*)d_in[0];   // (16,2048,512)
  const float* Wm     = (const float*)d_in[1];   // (1026,512)
  const float* bias   = (const float*)d_in[2];   // (1026,)
  const float* window = (const float*)d_in[3];   // (1024,)

  char* base = (char*)d_ws;
  ushort_t* Af     = (ushort_t*)base;                     // 33,554,432 B
  ushort_t* Whi    = (ushort_t*)(base + 33554432);        // 1,048,576 B
  __half*   frames = (__half*)base;                       // 67,108,864 B (reuses Af/W)
  __half*   coeffs = (__half*)(base + 67108864);          // 67,108,864 B

  convert_AB<<<2304, 256, 0, stream>>>(hs, Wm, bias, Af, Whi, coeffs);
  gemm_mfma<<<512, 1024, 0, stream>>>(Af, Whi, bias, coeffs);
  fft_win<<<FRAMES / 4, 256, 0, stream>>>(coeffs, frames, window);
  gather_out<<<8388608 / 256, 256, 0, stream>>>(frames, window, (float*)d_out);
}

// Round 10
// 150.136 us; speedup vs baseline: 1.1730x; 1.1730x over previous
//
#include <hip/hip_runtime.h>
#include <hip/hip_fp16.h>
#include <math.h>
#include <stdint.h>

// VocosISTFTHead on MI355X.
//  K0 convert_AB: fused. Blocks <2048: hs -> Af fp16 plane + Nyquist spec col
//                 (full f32 dot) -> coeffs slot[1]. Blocks >=2048: W -> tiled
//                 fp16 plane Whi [yb4][kt16][r256][k32].
//  K1 gemm_mfma : spec = hs @ W.T + b via single fp16 MFMA (Af x Whi).
//                 ROUND-8 structure (proven 57.5us): 256 rows x 128 pairs,
//                 512 thr / 8 waves (2M x 4N), A LDS triple-buffer, cross-phase
//                 frag prefetch, counted vmcnt (T4). THIS ROUND: single barrier
//                 per K-step (mid-phase SB removed; WAR on A-bufs still has 2
//                 step-top barriers between last read and rewrite).
//                 Round-6/9 lesson: do NOT raise occupancy by shrinking blocks
//                 or splitting waves — L2 locality + per-barrier compute rule.
//  K2 fft_win   : 1024-pt real iFFT per frame (512-pt complex Stockham radix-8),
//                 fp16 coeffs in (aligned 1024-half rows), fp16 frames out.
//  K3 gather_out: deterministic overlap-add gather + window^2 normalization.
// coeffs row layout (1024 halves, 2048B aligned): [0]=DC real, [1]=Nyquist real,
//   complex k (k=1..511) at halves [2k, 2k+2).
// ws (134.2 MB):
//   [0 : 33.55M) Af | [33.55M : 34.60M) Whi | later frames fp16 [0 : 67.11M)
//   [67.11M : 134.22M) coeffs fp16 (32768 x 1024 halves)

#define FRAMES  32768
#define TWO_PI  6.283185307179586f

typedef unsigned short ushort_t;
typedef __attribute__((ext_vector_type(8))) _Float16 f16x8;
typedef __attribute__((ext_vector_type(4))) float f32x4;

#define GLDS(gp, lp) __builtin_amdgcn_global_load_lds( \
    (const __attribute__((address_space(1))) void*)(gp), \
    (__attribute__((address_space(3))) void*)(lp), 16, 0, 0)

__device__ __forceinline__ float2 f2(float x, float y){ return make_float2(x,y); }
__device__ __forceinline__ float2 cadd(float2 a, float2 b){ return f2(a.x+b.x, a.y+b.y); }
__device__ __forceinline__ float2 csub(float2 a, float2 b){ return f2(a.x-b.x, a.y-b.y); }
__device__ __forceinline__ float2 cmul(float2 a, float2 b){ return f2(a.x*b.x - a.y*b.y, a.x*b.y + a.y*b.x); }

__device__ __forceinline__ uint32_t pack2h(float a, float b) {
  const ushort_t ha = __half_as_ushort(__float2half_rn(a));
  const ushort_t hb = __half_as_ushort(__float2half_rn(b));
  return (uint32_t)ha | ((uint32_t)hb << 16);
}

// ---------------------------------------------------------------------------
// K0: fused A/B conversion (unchanged, verified).
// ---------------------------------------------------------------------------
__global__ __launch_bounds__(256) void convert_AB(
    const float* __restrict__ hs, const float* __restrict__ Wm,
    const float* __restrict__ bias, ushort_t* __restrict__ Af,
    ushort_t* __restrict__ Whi, __half* __restrict__ coeffs)
{
  const int bid = blockIdx.x;
  const int t = threadIdx.x;
  if (bid < 2048) {
    const int r = t >> 4, c = t & 15;
    const int m = bid * 16 + r;
    const float* src = hs + (size_t)m * 512 + c * 32;
    const float* wm  = Wm + (size_t)512  * 512 + c * 32;
    const float* wp  = Wm + (size_t)1025 * 512 + c * 32;

    float v[32];
    #pragma unroll
    for (int i = 0; i < 8; ++i) *(float4*)&v[i*4] = *(const float4*)(src + i*4);

    float dm = 0.f, dp = 0.f;
    #pragma unroll
    for (int i = 0; i < 8; ++i) {
      const float4 a  = *(const float4*)&v[i*4];
      const float4 m4 = *(const float4*)(wm + i*4);
      const float4 p4 = *(const float4*)(wp + i*4);
      dm = fmaf(a.x,m4.x, fmaf(a.y,m4.y, fmaf(a.z,m4.z, fmaf(a.w,m4.w, dm))));
      dp = fmaf(a.x,p4.x, fmaf(a.y,p4.y, fmaf(a.z,p4.z, fmaf(a.w,p4.w, dp))));
    }

    uint32_t hu[16];
    #pragma unroll
    for (int i = 0; i < 16; ++i) hu[i] = pack2h(v[2*i], v[2*i+1]);
    ushort_t* dh = Af + (size_t)m * 512 + c * 32;
    #pragma unroll
    for (int q = 0; q < 4; ++q)
      *(uint4*)(dh + q*8) = make_uint4(hu[4*q], hu[4*q+1], hu[4*q+2], hu[4*q+3]);

    #pragma unroll
    for (int off = 8; off; off >>= 1) {
      dm += __shfl_xor(dm, off, 16);
      dp += __shfl_xor(dp, off, 16);
    }
    if (c == 0) {
      const float sm = dm + bias[512], sp = dp + bias[1025];
      const float mag = fminf(__expf(sm), 100.0f);
      coeffs[(size_t)m * 1024 + 1] = __float2half_rn(mag * __cosf(sp));
    }
  } else {
    const int gid = (bid - 2048) * 256 + t;
    const int sd = gid & 3;
    const int r  = (gid >> 2) & 255;
    const int kt = (gid >> 10) & 15;
    const int yb = gid >> 14;                        // 0..3
    const int srow = (r < 128) ? (yb*128 + r) : (513 + yb*128 + (r - 128));
    const float* src = Wm + (size_t)srow * 512 + kt*32 + sd*8;
    const float4 a = *(const float4*)src;
    const float4 b = *(const float4*)(src + 4);
    const uint4 o = make_uint4(pack2h(a.x,a.y), pack2h(a.z,a.w),
                               pack2h(b.x,b.y), pack2h(b.z,b.w));
    *(uint4*)(Whi + (size_t)gid * 8) = o;
  }
}

// ---------------------------------------------------------------------------
// K1: MFMA GEMM, 256 rows x 128 col-pairs, 512 threads, cross-phase prefetch,
//     ONE barrier per K-step.
// ---------------------------------------------------------------------------
__global__ __launch_bounds__(512, 2) void gemm_mfma(
    const ushort_t* __restrict__ Af, const ushort_t* __restrict__ Whi,
    const float* __restrict__ bias, __half* __restrict__ coeffs)
{
  __shared__ ushort_t Ab[24576];       // 3 bufs x (256r x 32k) fp16 = 48KB

  const int tid = threadIdx.x;
  const int w = tid >> 6, l = tid & 63;
  const int wr = w >> 2, wc = w & 3;         // wave grid 2M x 4N
  const int lc = l & 15, kg = l >> 4;        // frag row/col, k-octet

  const int bid = blockIdx.x;                // 512 = 8 XCD * 64
  const int swz = (bid & 7) * 64 + (bid >> 3);
  const int mb = swz >> 2, yb = swz & 3;     // 4 consecutive yb per mb per XCD

  // A staging: 2 chunks/thread; LDS linear, source inverse-swizzled
  // (sl = sd ^ ((r>>1)&3) => frag ds_read_b128 2-way max = free).
  uint32_t pa_off[2], lofs[2];
  #pragma unroll
  for (int ch = 0; ch < 2; ++ch) {
    const int g = ch*512 + tid;              // 0..1023
    const int r = g >> 2, sd = g & 3;
    lofs[ch] = r*32 + sd*8;                  // ushort units within a 16KB buf
    const int sl = sd ^ ((r >> 1) & 3);
    pa_off[ch] = (uint32_t)(mb*256 + r)*512 + sl*8;
  }
  // B fragment sources (regs, direct from L2-resident tiled plane)
  uint32_t pb_off[4];
  #pragma unroll
  for (int cf = 0; cf < 4; ++cf) {
    const int rB = ((cf < 2) ? 0 : 128) + wc*32 + (cf & 1)*16 + lc;
    pb_off[cf] = (uint32_t)yb*131072u + rB*32 + kg*8;
  }

  f32x4 acc[8][4];                   // [rf][cf]: cf 0,1 mag; 2,3 phase
  #pragma unroll
  for (int rf = 0; rf < 8; ++rf)
    #pragma unroll
    for (int cf = 0; cf < 4; ++cf)
      #pragma unroll
      for (int q = 0; q < 4; ++q) acc[rf][cf][q] = 0.f;

  const int asl = (kg ^ ((lc >> 1) & 3)) * 8;    // frag k-slot (rf-independent)

  f16x8 p[4], q[4];    // p: frags rf0-3 (phase0); q: frags rf4-7 (phase1)

#define WAITV2 asm volatile("s_waitcnt vmcnt(2) lgkmcnt(0)" ::: "memory")
#define WAITV0 asm volatile("s_waitcnt vmcnt(0) lgkmcnt(0)" ::: "memory")
#define SB     __builtin_amdgcn_s_barrier()
#define SCH0   __builtin_amdgcn_sched_barrier(0)

#define DSREAD(DST, BASE, RF0) do {                                      \
    _Pragma("unroll")                                                    \
    for (int r4 = 0; r4 < 4; ++r4) {                                     \
      const int rr = wr*128 + ((RF0) + r4)*16 + lc;                      \
      DST[r4] = *(const f16x8*)(&Ab[(BASE) + rr*32 + asl]);              \
    }                                                                    \
  } while (0)

#define MFMA16(FA, RF0, RB) do {                                         \
    __builtin_amdgcn_s_setprio(1);                                       \
    _Pragma("unroll")                                                    \
    for (int r4 = 0; r4 < 4; ++r4)                                       \
      _Pragma("unroll")                                                  \
      for (int cf = 0; cf < 4; ++cf)                                     \
        acc[(RF0)+r4][cf] = __builtin_amdgcn_mfma_f32_16x16x32_f16(      \
            FA[r4], RB[cf], acc[(RF0)+r4][cf], 0, 0, 0);                 \
    __builtin_amdgcn_s_setprio(0);                                       \
  } while (0)

  // Steady state at step top: outstanding (oldest->newest) =
  // [A(KT+1)c0, B(KT)b0, b1, A(KT+1)c1, b2, b3]; vmcnt(2) retires through
  // A(KT+1)c1 => aN fully staged before phase1's p-prefetch reads it; b2,b3
  // stay in flight across the barrier (T4), drained by the compiler's own
  // counted wait before the first MFMA that consumes them.
  // ONE barrier per step: WAR-safe because buffer read as aR in step s is
  // rewritten (as aW) in step s+2 — the step-top barriers of s+1 and s+2
  // (each preceded by lgkmcnt(0)) both separate read-complete from write.
#define ITER(KT, RBC, RBN, LAST) do {                                    \
    if (LAST) { WAITV0; } else { WAITV2; }                               \
    SB;                                                                  \
    /* phase 0: MFMA(p) ; prefetch q(this step ph1) from aR */           \
    DSREAD(q, aR, 4);                                                    \
    if ((KT) < 14) GLDS(Af + pa_off[0] + ((KT)+2)*32, &Ab[aW + lofs[0]]);\
    if ((KT) < 15) {                                                     \
      RBN[0] = *(const f16x8*)(Whi + pb_off[0] + ((KT)+1)*8192);         \
      RBN[1] = *(const f16x8*)(Whi + pb_off[1] + ((KT)+1)*8192);         \
    }                                                                    \
    SCH0;                                                                \
    MFMA16(p, 0, RBC);                                                   \
    /* phase 1 (no mid barrier): MFMA(q) ; prefetch p(next step) from aN */ \
    if ((KT) < 15) DSREAD(p, aN, 0);                                     \
    if ((KT) < 14) GLDS(Af + pa_off[1] + ((KT)+2)*32, &Ab[aW + lofs[1]]);\
    if ((KT) < 15) {                                                     \
      RBN[2] = *(const f16x8*)(Whi + pb_off[2] + ((KT)+1)*8192);         \
      RBN[3] = *(const f16x8*)(Whi + pb_off[3] + ((KT)+1)*8192);         \
    }                                                                    \
    SCH0;                                                                \
    MFMA16(q, 4, RBC);                                                   \
    { const unsigned t_ = aR; aR = aN; aN = aW; aW = t_; }               \
  } while (0)

  f16x8 rb0[4], rb1[4];
  // prologue: stage A(0)->buf0, A(1)->buf1, B(0)->rb0; then read p from buf0
  GLDS(Af + pa_off[0], &Ab[lofs[0]]);
  GLDS(Af + pa_off[1], &Ab[lofs[1]]);
  GLDS(Af + pa_off[0] + 32, &Ab[8192 + lofs[0]]);
  GLDS(Af + pa_off[1] + 32, &Ab[8192 + lofs[1]]);
  SCH0;
  #pragma unroll
  for (int j = 0; j < 4; ++j) rb0[j] = *(const f16x8*)(Whi + pb_off[j]);
  SCH0;
  asm volatile("s_waitcnt vmcnt(6)" ::: "memory");   // A(0) chunks retired
  SB;
  unsigned aR = 0, aN = 8192, aW = 16384;
  DSREAD(p, aR, 0);

  for (int k2 = 0; k2 < 8; ++k2) {
    ITER(2*k2,     rb0, rb1, false);
    ITER(2*k2 + 1, rb1, rb0, k2 == 7);
  }
#undef ITER
#undef DSREAD
#undef MFMA16

  // Epilogue. C/D 16x16: col = lane&15, row = (lane>>4)*4 + qi.
  // coeffs row: [0]=DC real, [1]=Nyq real, complex k at [2k] (k=1..511).
  #pragma unroll
  for (int j = 0; j < 2; ++j) {
    const int pcol = yb*128 + wc*32 + j*16 + lc;       // 0..511
    const float bm = bias[pcol], bp = bias[513 + pcol];
    #pragma unroll
    for (int rf = 0; rf < 8; ++rf) {
      const int rbase = mb*256 + wr*128 + rf*16 + kg*4;
      #pragma unroll
      for (int qi = 0; qi < 4; ++qi) {
        const float sm = acc[rf][j][qi]   + bm;
        const float sp = acc[rf][2+j][qi] + bp;
        const float mag = fminf(__expf(sm), 100.0f);
        const float aa = mag * __cosf(sp);
        const float bb = mag * __sinf(sp);
        __half* row = coeffs + (size_t)(rbase + qi) * 1024;
        if (pcol == 0) row[0] = __float2half_rn(aa);   // DC real (imag dropped)
        else *(__half2*)(row + 2*pcol) = __float22half2_rn(make_float2(aa, bb));
      }
    }
  }
}

// ---------------------------------------------------------------------------
// K2: per-frame irfft(1024) + window. fp16 coeffs in, fp16 frames out.
// ---------------------------------------------------------------------------
#define PIDX(s) ((s) + ((s) >> 3))

template<int NS>
__device__ __forceinline__ void stage_fft(const float2* in, float2* out, int l)
{
  float2 v[8];
  #pragma unroll
  for (int r = 0; r < 8; ++r) v[r] = in[PIDX(l + 64*r)];
  if (NS > 1) {
    const float ang = TWO_PI * (float)(l & (NS-1)) / (float)(NS * 8);
    float sn, cs; __sincosf(ang, &sn, &cs);
    const float2 wb = f2(cs, sn);
    float2 cur = wb;
    #pragma unroll
    for (int r = 1; r < 8; ++r) { v[r] = cmul(v[r], cur); cur = cmul(cur, wb); }
  }
  const float2 e0=v[0], e1=v[2], e2=v[4], e3=v[6];
  const float2 o0=v[1], o1=v[3], o2=v[5], o3=v[7];
  float2 a = cadd(e0,e2), b = csub(e0,e2), c = cadd(e1,e3), d = csub(e1,e3);
  const float2 E0 = cadd(a,c), E2 = csub(a,c);
  const float2 E1 = f2(b.x - d.y, b.y + d.x), E3 = f2(b.x + d.y, b.y - d.x);
  a = cadd(o0,o2); b = csub(o0,o2); c = cadd(o1,o3); d = csub(o1,o3);
  const float2 O0 = cadd(a,c), O2 = csub(a,c);
  const float2 O1 = f2(b.x - d.y, b.y + d.x), O3 = f2(b.x + d.y, b.y - d.x);
  const float r2 = 0.70710678118654752f;
  const float2 t0 = O0;
  const float2 t1 = f2(r2*(O1.x - O1.y),  r2*(O1.x + O1.y));
  const float2 t2 = f2(-O2.y, O2.x);
  const float2 t3 = f2(-r2*(O3.x + O3.y), r2*(O3.x - O3.y));
  float2 X[8];
  X[0]=cadd(E0,t0); X[4]=csub(E0,t0);
  X[1]=cadd(E1,t1); X[5]=csub(E1,t1);
  X[2]=cadd(E2,t2); X[6]=csub(E2,t2);
  X[3]=cadd(E3,t3); X[7]=csub(E3,t3);
  const int idxD = (l / NS) * (NS * 8) + (l & (NS-1));
  #pragma unroll
  for (int q = 0; q < 8; ++q) out[PIDX(idxD + q*NS)] = X[q];
}

__global__ __launch_bounds__(256) void fft_win(
    const __half* coeffs, __half* frames, const float* __restrict__ window)
{
  __shared__ float2 bA[4][576];
  __shared__ float2 bB[4][576];
  const int tid = threadIdx.x;
  const int w = tid >> 6, l = tid & 63;
  const size_t f = (size_t)blockIdx.x * 4 + w;
  const __half2* crow = (const __half2*)(coeffs + f * 1024);

  const float sc = 1.0f / 1024.0f;
  #pragma unroll
  for (int j = 0; j < 4; ++j) {
    const int k = 1 + l + 64*j;
    const float2 Ck = __half22float2(crow[k]);
    const float2 Cq = __half22float2(crow[512-k]);
    float sn, cs; __sincosf(TWO_PI * (1.0f/1024.0f) * (float)k, &sn, &cs);
    const float Ex = sc*(Ck.x + Cq.x), Ey = sc*(Ck.y - Cq.y);
    const float Dx = Ck.x - Cq.x,      Dy = Ck.y + Cq.y;
    const float Ox = sc*(cs*Dx - sn*Dy), Oy = sc*(cs*Dy + sn*Dx);
    bA[w][PIDX(k)]     = f2(Ex - Oy, Ey + Ox);
    bA[w][PIDX(512-k)] = f2(Ex + Oy, Ox - Ey);
  }
  if (l == 0) {
    const float2 dn = __half22float2(crow[0]);   // (DC real, Nyq real)
    bA[w][PIDX(0)] = f2(sc*(dn.x + dn.y), sc*(dn.x - dn.y));
  }
  __syncthreads();
  stage_fft<1 >(bA[w], bB[w], l);
  __syncthreads();
  stage_fft<8 >(bB[w], bA[w], l);
  __syncthreads();
  stage_fft<64>(bA[w], bB[w], l);
  __syncthreads();

  __half2* frow = (__half2*)(frames + f * 1024);
  #pragma unroll
  for (int j = 0; j < 8; ++j) {
    const int m = l + 64*j;
    const float2 z  = bB[w][PIDX(m)];
    const float2 wv = *(const float2*)(window + 2*m);
    frow[m] = __float22half2_rn(make_float2(z.x * wv.x, z.y * wv.y));
  }
}

// ---------------------------------------------------------------------------
// K3: overlap-add gather + normalization. fp16 frames in, f32 out.
// ---------------------------------------------------------------------------
__global__ __launch_bounds__(256) void gather_out(
    const __half* __restrict__ frames, const float* __restrict__ window,
    float* __restrict__ out)
{
  const int idx = blockIdx.x * 256 + threadIdx.x;
  const int b  = idx >> 19;
  const int jj = idx & 524287;
  const int s  = jj + 384;
  int tlo = (s - 768) >> 8; if (tlo < 0) tlo = 0;
  int thi = s >> 8;         if (thi > 2047) thi = 2047;
  float acc = 0.f, nrm = 0.f;
  for (int t = tlo; t <= thi; ++t) {
    const int n = s - (t << 8);
    const float wv = window[n];
    nrm = fmaf(wv, wv, nrm);
    acc += __half2float(frames[(size_t)(b * 2048 + t) * 1024 + n]);
  }
  out[idx] = acc / nrm;
}

// ---------------------------------------------------------------------------
extern "C" void kernel_launch(void* const* d_in, const int* in_sizes, int n_in,
                              void* d_out, int out_size, void* d_ws, size_t ws_size,
                              hipStream_t stream)
{
  const float* hs     = (const float*)d_in[0];   // (16,2048,512)
  const float* Wm     = (const float*)d_in[1];   // (1026,512)
  const float* bias   = (const float*)d_in[2];   // (1026,)
  const float* window = (const float*)d_in[3];   // (1024,)

  char* base = (char*)d_ws;
  ushort_t* Af     = (ushort_t*)base;                     // 33,554,432 B
  ushort_t* Whi    = (ushort_t*)(base + 33554432);        // 1,048,576 B
  __half*   frames = (__half*)base;                       // 67,108,864 B (reuses Af/W)
  __half*   coeffs = (__half*)(base + 67108864);          // 67,108,864 B

  convert_AB<<<2304, 256, 0, stream>>>(hs, Wm, bias, Af, Whi, coeffs);
  gemm_mfma<<<512,  512, 0, stream>>>(Af, Whi, bias, coeffs);
  fft_win<<<FRAMES / 4, 256, 0, stream>>>(coeffs, frames, window);
  gather_out<<<8388608 / 256, 256, 0, stream>>>(frames, window, (float*)d_out);
}

// Round 11
// 134.169 us; speedup vs baseline: 1.3126x; 1.1190x over previous
//
#include <hip/hip_runtime.h>
#include <hip/hip_fp16.h>
#include <math.h>
#include <stdint.h>

// VocosISTFTHead on MI355X.
//  K0 convert_AB: fused. Blocks <2048: hs -> Af fp16 plane + Nyquist spec col
//                 (full f32 dot) -> coeffs slot[1]. Blocks >=2048: W -> tiled
//                 fp16 plane Whi [yb4][kt16][r256][k32].
//  K1 gemm_mfma : spec = hs @ W.T + b via single fp16 MFMA (Af x Whi).
//                 Round-10 structure (proven 55.4us): 256 rows x 128 pairs,
//                 512 thr / 8 waves (2M x 4N), A LDS triple-buffer, cross-phase
//                 frag prefetch, counted vmcnt (T4), ONE barrier per K-step.
//                 THIS ROUND: epilogue stores reordered so each 128B coeff-line
//                 is written by temporally-adjacent 64B stores (kills the
//                 94MB->67MB write amplification seen in WRITE_SIZE).
//  K2 fft_win   : 1024-pt real iFFT per frame (512-pt complex Stockham radix-8).
//                 THIS ROUND: barrier-free — each wave owns its LDS slice; DS
//                 pipe is in-order per wave, so wave_barrier (compiler fence,
//                 0 instructions) replaces __syncthreads.
//  K3 gather_out: deterministic overlap-add gather + window^2 normalization.
//                 THIS ROUND: 4 outputs/thread (aligned, never straddles a
//                 hop boundary) -> uint2/float4 vector loads, float4 store.
// coeffs row layout (1024 halves, 2048B aligned): [0]=DC real, [1]=Nyquist real,
//   complex k (k=1..511) at halves [2k, 2k+2).
// ws (134.2 MB):
//   [0 : 33.55M) Af | [33.55M : 34.60M) Whi | later frames fp16 [0 : 67.11M)
//   [67.11M : 134.22M) coeffs fp16 (32768 x 1024 halves)

#define FRAMES  32768
#define TWO_PI  6.283185307179586f

typedef unsigned short ushort_t;
typedef __attribute__((ext_vector_type(8))) _Float16 f16x8;
typedef __attribute__((ext_vector_type(4))) float f32x4;

#define GLDS(gp, lp) __builtin_amdgcn_global_load_lds( \
    (const __attribute__((address_space(1))) void*)(gp), \
    (__attribute__((address_space(3))) void*)(lp), 16, 0, 0)

__device__ __forceinline__ float2 f2(float x, float y){ return make_float2(x,y); }
__device__ __forceinline__ float2 cadd(float2 a, float2 b){ return f2(a.x+b.x, a.y+b.y); }
__device__ __forceinline__ float2 csub(float2 a, float2 b){ return f2(a.x-b.x, a.y-b.y); }
__device__ __forceinline__ float2 cmul(float2 a, float2 b){ return f2(a.x*b.x - a.y*b.y, a.x*b.y + a.y*b.x); }

__device__ __forceinline__ uint32_t pack2h(float a, float b) {
  const ushort_t ha = __half_as_ushort(__float2half_rn(a));
  const ushort_t hb = __half_as_ushort(__float2half_rn(b));
  return (uint32_t)ha | ((uint32_t)hb << 16);
}

// ---------------------------------------------------------------------------
// K0: fused A/B conversion (unchanged, verified).
// ---------------------------------------------------------------------------
__global__ __launch_bounds__(256) void convert_AB(
    const float* __restrict__ hs, const float* __restrict__ Wm,
    const float* __restrict__ bias, ushort_t* __restrict__ Af,
    ushort_t* __restrict__ Whi, __half* __restrict__ coeffs)
{
  const int bid = blockIdx.x;
  const int t = threadIdx.x;
  if (bid < 2048) {
    const int r = t >> 4, c = t & 15;
    const int m = bid * 16 + r;
    const float* src = hs + (size_t)m * 512 + c * 32;
    const float* wm  = Wm + (size_t)512  * 512 + c * 32;
    const float* wp  = Wm + (size_t)1025 * 512 + c * 32;

    float v[32];
    #pragma unroll
    for (int i = 0; i < 8; ++i) *(float4*)&v[i*4] = *(const float4*)(src + i*4);

    float dm = 0.f, dp = 0.f;
    #pragma unroll
    for (int i = 0; i < 8; ++i) {
      const float4 a  = *(const float4*)&v[i*4];
      const float4 m4 = *(const float4*)(wm + i*4);
      const float4 p4 = *(const float4*)(wp + i*4);
      dm = fmaf(a.x,m4.x, fmaf(a.y,m4.y, fmaf(a.z,m4.z, fmaf(a.w,m4.w, dm))));
      dp = fmaf(a.x,p4.x, fmaf(a.y,p4.y, fmaf(a.z,p4.z, fmaf(a.w,p4.w, dp))));
    }

    uint32_t hu[16];
    #pragma unroll
    for (int i = 0; i < 16; ++i) hu[i] = pack2h(v[2*i], v[2*i+1]);
    ushort_t* dh = Af + (size_t)m * 512 + c * 32;
    #pragma unroll
    for (int q = 0; q < 4; ++q)
      *(uint4*)(dh + q*8) = make_uint4(hu[4*q], hu[4*q+1], hu[4*q+2], hu[4*q+3]);

    #pragma unroll
    for (int off = 8; off; off >>= 1) {
      dm += __shfl_xor(dm, off, 16);
      dp += __shfl_xor(dp, off, 16);
    }
    if (c == 0) {
      const float sm = dm + bias[512], sp = dp + bias[1025];
      const float mag = fminf(__expf(sm), 100.0f);
      coeffs[(size_t)m * 1024 + 1] = __float2half_rn(mag * __cosf(sp));
    }
  } else {
    const int gid = (bid - 2048) * 256 + t;
    const int sd = gid & 3;
    const int r  = (gid >> 2) & 255;
    const int kt = (gid >> 10) & 15;
    const int yb = gid >> 14;                        // 0..3
    const int srow = (r < 128) ? (yb*128 + r) : (513 + yb*128 + (r - 128));
    const float* src = Wm + (size_t)srow * 512 + kt*32 + sd*8;
    const float4 a = *(const float4*)src;
    const float4 b = *(const float4*)(src + 4);
    const uint4 o = make_uint4(pack2h(a.x,a.y), pack2h(a.z,a.w),
                               pack2h(b.x,b.y), pack2h(b.z,b.w));
    *(uint4*)(Whi + (size_t)gid * 8) = o;
  }
}

// ---------------------------------------------------------------------------
// K1: MFMA GEMM, 256 rows x 128 col-pairs, 512 threads, cross-phase prefetch,
//     one barrier per K-step, line-coalesced epilogue stores.
// ---------------------------------------------------------------------------
__global__ __launch_bounds__(512, 2) void gemm_mfma(
    const ushort_t* __restrict__ Af, const ushort_t* __restrict__ Whi,
    const float* __restrict__ bias, __half* __restrict__ coeffs)
{
  __shared__ ushort_t Ab[24576];       // 3 bufs x (256r x 32k) fp16 = 48KB

  const int tid = threadIdx.x;
  const int w = tid >> 6, l = tid & 63;
  const int wr = w >> 2, wc = w & 3;         // wave grid 2M x 4N
  const int lc = l & 15, kg = l >> 4;        // frag row/col, k-octet

  const int bid = blockIdx.x;                // 512 = 8 XCD * 64
  const int swz = (bid & 7) * 64 + (bid >> 3);
  const int mb = swz >> 2, yb = swz & 3;     // 4 consecutive yb per mb per XCD

  // A staging: 2 chunks/thread; LDS linear, source inverse-swizzled
  // (sl = sd ^ ((r>>1)&3) => frag ds_read_b128 2-way max = free).
  uint32_t pa_off[2], lofs[2];
  #pragma unroll
  for (int ch = 0; ch < 2; ++ch) {
    const int g = ch*512 + tid;              // 0..1023
    const int r = g >> 2, sd = g & 3;
    lofs[ch] = r*32 + sd*8;                  // ushort units within a 16KB buf
    const int sl = sd ^ ((r >> 1) & 3);
    pa_off[ch] = (uint32_t)(mb*256 + r)*512 + sl*8;
  }
  // B fragment sources (regs, direct from L2-resident tiled plane)
  uint32_t pb_off[4];
  #pragma unroll
  for (int cf = 0; cf < 4; ++cf) {
    const int rB = ((cf < 2) ? 0 : 128) + wc*32 + (cf & 1)*16 + lc;
    pb_off[cf] = (uint32_t)yb*131072u + rB*32 + kg*8;
  }

  f32x4 acc[8][4];                   // [rf][cf]: cf 0,1 mag; 2,3 phase
  #pragma unroll
  for (int rf = 0; rf < 8; ++rf)
    #pragma unroll
    for (int cf = 0; cf < 4; ++cf)
      #pragma unroll
      for (int q = 0; q < 4; ++q) acc[rf][cf][q] = 0.f;

  const int asl = (kg ^ ((lc >> 1) & 3)) * 8;    // frag k-slot (rf-independent)

  f16x8 p[4], q[4];    // p: frags rf0-3 (phase0); q: frags rf4-7 (phase1)

#define WAITV2 asm volatile("s_waitcnt vmcnt(2) lgkmcnt(0)" ::: "memory")
#define WAITV0 asm volatile("s_waitcnt vmcnt(0) lgkmcnt(0)" ::: "memory")
#define SB     __builtin_amdgcn_s_barrier()
#define SCH0   __builtin_amdgcn_sched_barrier(0)

#define DSREAD(DST, BASE, RF0) do {                                      \
    _Pragma("unroll")                                                    \
    for (int r4 = 0; r4 < 4; ++r4) {                                     \
      const int rr = wr*128 + ((RF0) + r4)*16 + lc;                      \
      DST[r4] = *(const f16x8*)(&Ab[(BASE) + rr*32 + asl]);              \
    }                                                                    \
  } while (0)

#define MFMA16(FA, RF0, RB) do {                                         \
    __builtin_amdgcn_s_setprio(1);                                       \
    _Pragma("unroll")                                                    \
    for (int r4 = 0; r4 < 4; ++r4)                                       \
      _Pragma("unroll")                                                  \
      for (int cf = 0; cf < 4; ++cf)                                     \
        acc[(RF0)+r4][cf] = __builtin_amdgcn_mfma_f32_16x16x32_f16(      \
            FA[r4], RB[cf], acc[(RF0)+r4][cf], 0, 0, 0);                 \
    __builtin_amdgcn_s_setprio(0);                                       \
  } while (0)

  // Steady state at step top: outstanding (oldest->newest) =
  // [A(KT+1)c0, B(KT)b0, b1, A(KT+1)c1, b2, b3]; vmcnt(2) retires through
  // A(KT+1)c1 => aN fully staged before phase1's p-prefetch reads it; b2,b3
  // stay in flight across the barrier (T4). ONE barrier per step: WAR-safe
  // because buffer read as aR in step s is rewritten (as aW) in step s+2 —
  // the step-top barriers of s+1 and s+2 both separate read from rewrite.
#define ITER(KT, RBC, RBN, LAST) do {                                    \
    if (LAST) { WAITV0; } else { WAITV2; }                               \
    SB;                                                                  \
    /* phase 0: MFMA(p) ; prefetch q(this step ph1) from aR */           \
    DSREAD(q, aR, 4);                                                    \
    if ((KT) < 14) GLDS(Af + pa_off[0] + ((KT)+2)*32, &Ab[aW + lofs[0]]);\
    if ((KT) < 15) {                                                     \
      RBN[0] = *(const f16x8*)(Whi + pb_off[0] + ((KT)+1)*8192);         \
      RBN[1] = *(const f16x8*)(Whi + pb_off[1] + ((KT)+1)*8192);         \
    }                                                                    \
    SCH0;                                                                \
    MFMA16(p, 0, RBC);                                                   \
    /* phase 1 (no mid barrier): MFMA(q) ; prefetch p(next step) from aN */ \
    if ((KT) < 15) DSREAD(p, aN, 0);                                     \
    if ((KT) < 14) GLDS(Af + pa_off[1] + ((KT)+2)*32, &Ab[aW + lofs[1]]);\
    if ((KT) < 15) {                                                     \
      RBN[2] = *(const f16x8*)(Whi + pb_off[2] + ((KT)+1)*8192);         \
      RBN[3] = *(const f16x8*)(Whi + pb_off[3] + ((KT)+1)*8192);         \
    }                                                                    \
    SCH0;                                                                \
    MFMA16(q, 4, RBC);                                                   \
    { const unsigned t_ = aR; aR = aN; aN = aW; aW = t_; }               \
  } while (0)

  f16x8 rb0[4], rb1[4];
  // prologue: stage A(0)->buf0, A(1)->buf1, B(0)->rb0; then read p from buf0
  GLDS(Af + pa_off[0], &Ab[lofs[0]]);
  GLDS(Af + pa_off[1], &Ab[lofs[1]]);
  GLDS(Af + pa_off[0] + 32, &Ab[8192 + lofs[0]]);
  GLDS(Af + pa_off[1] + 32, &Ab[8192 + lofs[1]]);
  SCH0;
  #pragma unroll
  for (int j = 0; j < 4; ++j) rb0[j] = *(const f16x8*)(Whi + pb_off[j]);
  SCH0;
  asm volatile("s_waitcnt vmcnt(6)" ::: "memory");   // A(0) chunks retired
  SB;
  unsigned aR = 0, aN = 8192, aW = 16384;
  DSREAD(p, aR, 0);

  for (int k2 = 0; k2 < 8; ++k2) {
    ITER(2*k2,     rb0, rb1, false);
    ITER(2*k2 + 1, rb1, rb0, k2 == 7);
  }
#undef ITER
#undef DSREAD
#undef MFMA16

  // Epilogue. C/D 16x16: col = lane&15, row = (lane>>4)*4 + qi.
  // coeffs row: [0]=DC real, [1]=Nyq real, complex k at [2k] (k=1..511).
  // j innermost: the two 64B halves of each 128B line land back-to-back.
  const int pc0 = yb*128 + wc*32 + lc;               // j=0 col, 0..511
  const int pc1 = pc0 + 16;                          // j=1 col, never 0
  const float bm0 = bias[pc0], bp0 = bias[513 + pc0];
  const float bm1 = bias[pc1], bp1 = bias[513 + pc1];
  #pragma unroll
  for (int rf = 0; rf < 8; ++rf) {
    const int rbase = mb*256 + wr*128 + rf*16 + kg*4;
    #pragma unroll
    for (int qi = 0; qi < 4; ++qi) {
      __half* row = coeffs + (size_t)(rbase + qi) * 1024;
      {
        const float sm = acc[rf][0][qi] + bm0;
        const float sp = acc[rf][2][qi] + bp0;
        const float mag = fminf(__expf(sm), 100.0f);
        const float aa = mag * __cosf(sp);
        const float bb = mag * __sinf(sp);
        if (pc0 == 0) row[0] = __float2half_rn(aa);  // DC real (imag dropped)
        else *(__half2*)(row + 2*pc0) = __float22half2_rn(make_float2(aa, bb));
      }
      {
        const float sm = acc[rf][1][qi] + bm1;
        const float sp = acc[rf][3][qi] + bp1;
        const float mag = fminf(__expf(sm), 100.0f);
        const float aa = mag * __cosf(sp);
        const float bb = mag * __sinf(sp);
        *(__half2*)(row + 2*pc1) = __float22half2_rn(make_float2(aa, bb));
      }
    }
  }
}

// ---------------------------------------------------------------------------
// K2: per-frame irfft(1024) + window. Barrier-free: each wave owns its LDS
// slice; DS pipe is in-order per wave, so a compiler fence (wave_barrier)
// suffices for write->read ordering. fp16 coeffs in, fp16 frames out.
// ---------------------------------------------------------------------------
#define PIDX(s) ((s) + ((s) >> 3))
#define WFENCE  __builtin_amdgcn_wave_barrier()

template<int NS>
__device__ __forceinline__ void stage_fft(const float2* in, float2* out, int l)
{
  float2 v[8];
  #pragma unroll
  for (int r = 0; r < 8; ++r) v[r] = in[PIDX(l + 64*r)];
  if (NS > 1) {
    const float ang = TWO_PI * (float)(l & (NS-1)) / (float)(NS * 8);
    float sn, cs; __sincosf(ang, &sn, &cs);
    const float2 wb = f2(cs, sn);
    float2 cur = wb;
    #pragma unroll
    for (int r = 1; r < 8; ++r) { v[r] = cmul(v[r], cur); cur = cmul(cur, wb); }
  }
  const float2 e0=v[0], e1=v[2], e2=v[4], e3=v[6];
  const float2 o0=v[1], o1=v[3], o2=v[5], o3=v[7];
  float2 a = cadd(e0,e2), b = csub(e0,e2), c = cadd(e1,e3), d = csub(e1,e3);
  const float2 E0 = cadd(a,c), E2 = csub(a,c);
  const float2 E1 = f2(b.x - d.y, b.y + d.x), E3 = f2(b.x + d.y, b.y - d.x);
  a = cadd(o0,o2); b = csub(o0,o2); c = cadd(o1,o3); d = csub(o1,o3);
  const float2 O0 = cadd(a,c), O2 = csub(a,c);
  const float2 O1 = f2(b.x - d.y, b.y + d.x), O3 = f2(b.x + d.y, b.y - d.x);
  const float r2 = 0.70710678118654752f;
  const float2 t0 = O0;
  const float2 t1 = f2(r2*(O1.x - O1.y),  r2*(O1.x + O1.y));
  const float2 t2 = f2(-O2.y, O2.x);
  const float2 t3 = f2(-r2*(O3.x + O3.y), r2*(O3.x - O3.y));
  float2 X[8];
  X[0]=cadd(E0,t0); X[4]=csub(E0,t0);
  X[1]=cadd(E1,t1); X[5]=csub(E1,t1);
  X[2]=cadd(E2,t2); X[6]=csub(E2,t2);
  X[3]=cadd(E3,t3); X[7]=csub(E3,t3);
  const int idxD = (l / NS) * (NS * 8) + (l & (NS-1));
  #pragma unroll
  for (int q = 0; q < 8; ++q) out[PIDX(idxD + q*NS)] = X[q];
}

__global__ __launch_bounds__(256) void fft_win(
    const __half* coeffs, __half* frames, const float* __restrict__ window)
{
  __shared__ float2 bA[4][576];
  __shared__ float2 bB[4][576];
  const int tid = threadIdx.x;
  const int w = tid >> 6, l = tid & 63;
  const size_t f = (size_t)blockIdx.x * 4 + w;
  const __half2* crow = (const __half2*)(coeffs + f * 1024);

  const float sc = 1.0f / 1024.0f;
  #pragma unroll
  for (int j = 0; j < 4; ++j) {
    const int k = 1 + l + 64*j;
    const float2 Ck = __half22float2(crow[k]);
    const float2 Cq = __half22float2(crow[512-k]);
    float sn, cs; __sincosf(TWO_PI * (1.0f/1024.0f) * (float)k, &sn, &cs);
    const float Ex = sc*(Ck.x + Cq.x), Ey = sc*(Ck.y - Cq.y);
    const float Dx = Ck.x - Cq.x,      Dy = Ck.y + Cq.y;
    const float Ox = sc*(cs*Dx - sn*Dy), Oy = sc*(cs*Dy + sn*Dx);
    bA[w][PIDX(k)]     = f2(Ex - Oy, Ey + Ox);
    bA[w][PIDX(512-k)] = f2(Ex + Oy, Ox - Ey);
  }
  if (l == 0) {
    const float2 dn = __half22float2(crow[0]);   // (DC real, Nyq real)
    bA[w][PIDX(0)] = f2(sc*(dn.x + dn.y), sc*(dn.x - dn.y));
  }
  WFENCE;
  stage_fft<1 >(bA[w], bB[w], l);
  WFENCE;
  stage_fft<8 >(bB[w], bA[w], l);
  WFENCE;
  stage_fft<64>(bA[w], bB[w], l);
  WFENCE;

  __half2* frow = (__half2*)(frames + f * 1024);
  #pragma unroll
  for (int j = 0; j < 8; ++j) {
    const int m = l + 64*j;
    const float2 z  = bB[w][PIDX(m)];
    const float2 wv = *(const float2*)(window + 2*m);
    frow[m] = __float22half2_rn(make_float2(z.x * wv.x, z.y * wv.y));
  }
}

// ---------------------------------------------------------------------------
// K3: overlap-add gather + normalization. 4 outputs/thread (s0 % 4 == 0, so
// the quad never straddles a hop boundary -> shared t-range, vector loads).
// ---------------------------------------------------------------------------
__global__ __launch_bounds__(256) void gather_out(
    const __half* __restrict__ frames, const float* __restrict__ window,
    float* __restrict__ out)
{
  const int idx = blockIdx.x * 256 + threadIdx.x;     // 2,097,152 total
  const int b  = idx >> 17;                           // batch
  const int g  = idx & 131071;
  const int s  = g * 4 + 384;                         // first sample of quad
  int tlo = (s - 768) >> 8; if (tlo < 0) tlo = 0;
  int thi = s >> 8;         if (thi > 2047) thi = 2047;
  float a0=0.f, a1=0.f, a2=0.f, a3=0.f;
  float n0=0.f, n1=0.f, n2=0.f, n3=0.f;
  const __half* fb = frames + (size_t)b * 2048 * 1024;
  for (int t = tlo; t <= thi; ++t) {
    const int n = s - (t << 8);
    const float4 wv = *(const float4*)(window + n);
    const uint2 fr = *(const uint2*)(fb + (size_t)t * 1024 + n);
    const float2 f01 = __half22float2(*(const __half2*)&fr.x);
    const float2 f23 = __half22float2(*(const __half2*)&fr.y);
    a0 += f01.x; a1 += f01.y; a2 += f23.x; a3 += f23.y;
    n0 = fmaf(wv.x, wv.x, n0); n1 = fmaf(wv.y, wv.y, n1);
    n2 = fmaf(wv.z, wv.z, n2); n3 = fmaf(wv.w, wv.w, n3);
  }
  *(float4*)(out + (size_t)idx * 4) = make_float4(a0/n0, a1/n1, a2/n2, a3/n3);
}

// ---------------------------------------------------------------------------
extern "C" void kernel_launch(void* const* d_in, const int* in_sizes, int n_in,
                              void* d_out, int out_size, void* d_ws, size_t ws_size,
                              hipStream_t stream)
{
  const float* hs     = (const float*)d_in[0];   // (16,2048,512)
  const float* Wm     = (const float*)d_in[1];   // (1026,512)
  const float* bias   = (const float*)d_in[2];   // (1026,)
  const float* window = (const float*)d_in[3];   // (1024,)

  char* base = (char*)d_ws;
  ushort_t* Af     = (ushort_t*)base;                     // 33,554,432 B
  ushort_t* Whi    = (ushort_t*)(base + 33554432);        // 1,048,576 B
  __half*   frames = (__half*)base;                       // 67,108,864 B (reuses Af/W)
  __half*   coeffs = (__half*)(base + 67108864);          // 67,108,864 B

  convert_AB<<<2304, 256, 0, stream>>>(hs, Wm, bias, Af, Whi, coeffs);
  gemm_mfma<<<512,  512, 0, stream>>>(Af, Whi, bias, coeffs);
  fft_win<<<FRAMES / 4, 256, 0, stream>>>(coeffs, frames, window);
  gather_out<<<8192, 256, 0, stream>>>(frames, window, (float*)d_out);
}